// Round 1
// baseline (59.026 us; speedup 1.0000x reference)
//
#include <hip/hip_runtime.h>

// Problem constants (fixed by setup_inputs): B=16, T=1024, D=256, SCALE=8 -> N=128
constexpr int B = 16;
constexpr int T = 1024;
constexpr int D = 256;
constexpr int N = 128;      // T / SCALE
constexpr int D4 = D / 4;   // 64 float4 per row
constexpr float NEG_INF_V = -1e30f;

__device__ __forceinline__ float4 max4(float4 a, float4 b) {
    return make_float4(fmaxf(a.x, b.x), fmaxf(a.y, b.y), fmaxf(a.z, b.z), fmaxf(a.w, b.w));
}

// Kernel M: per-batch scaled_mask (window-8 max) and lengths (sum of mask, as int)
__global__ void mask_stats_kernel(const float* __restrict__ mask,
                                  float* __restrict__ smask,
                                  int* __restrict__ lengths) {
    int b = blockIdx.x;       // B blocks
    int n = threadIdx.x;      // 128 threads, one per pooled position
    const float* mrow = mask + (size_t)b * T + (size_t)n * 8;
    float mx = -INFINITY;
    float sum = 0.0f;
#pragma unroll
    for (int t = 0; t < 8; ++t) {
        float v = mrow[t];
        mx = fmaxf(mx, v);
        sum += v;
    }
    smask[b * N + n] = mx;
    __shared__ float red[128];
    red[n] = sum;
    __syncthreads();
    for (int s = 64; s > 0; s >>= 1) {
        if (n < s) red[n] += red[n + s];
        __syncthreads();
    }
    if (n == 0) lengths[b] = (int)red[0];
}

// Kernel A: pooled[b][n][d] = max over 8 frames of (feats + (1-mask)*NEG_INF)
// grid: B*N/4 blocks, 256 threads. Each 64-lane wave handles one n row (float4 over d).
__global__ __launch_bounds__(256) void pool_feats_kernel(const float4* __restrict__ feats,
                                                         const float* __restrict__ mask,
                                                         float4* __restrict__ pooled) {
    int tid = threadIdx.x;
    int nloc = tid >> 6;       // 0..3
    int lane = tid & 63;       // float4 index over D
    int gidx = blockIdx.x * 4 + nloc;  // b*N + n
    int b = gidx >> 7;
    int n = gidx & (N - 1);
    const float* mrow = mask + (size_t)b * T + (size_t)n * 8;
    const float4* frow = feats + ((size_t)b * T + (size_t)n * 8) * D4 + lane;
    float4 acc = make_float4(-INFINITY, -INFINITY, -INFINITY, -INFINITY);
#pragma unroll
    for (int t = 0; t < 8; ++t) {
        float add = (1.0f - mrow[t]) * NEG_INF_V;
        float4 v = frow[(size_t)t * D4];
        float4 vv = make_float4(v.x + add, v.y + add, v.z + add, v.w + add);
        acc = max4(acc, vv);
    }
    pooled[(size_t)gidx * D4 + lane] = acc;
}

// Kernel B: fill feat2d output. One block per (b,s); 4 waves; wave w owns e ≡ pattern.
// Band cells (s <= e <= s+15, e < N): running max of pooled over [s..e], times smask[e].
// All other e: zero. Every cell written every call (d_out is poisoned once).
__global__ __launch_bounds__(256) void fill_feat2d_kernel(const float4* __restrict__ pooled,
                                                          const float* __restrict__ smask,
                                                          float4* __restrict__ out) {
    int blk = blockIdx.x;          // b*N + s
    int b = blk >> 7;
    int s = blk & (N - 1);
    int w = threadIdx.x >> 6;      // wave id 0..3
    int lane = threadIdx.x & 63;   // float4 index over D

    float4 zero = make_float4(0.f, 0.f, 0.f, 0.f);
    float4* orow = out + ((size_t)blk * N) * D4 + lane;   // index by + e*D4

    // Zero region: wave w covers e = w, w+4, ... ; skip band cells (written below).
    int band_hi = s + 15;
    for (int e = w; e < N; e += 4) {
        if (e >= s && e <= band_hi) continue;     // wave-uniform branch
        orow[(size_t)e * D4] = zero;
    }

    // Band: wave w writes offsets w, w+4, w+8, w+12 with prefix running max.
    const float4* prow = pooled + ((size_t)b * N) * D4 + lane;
    const float* sm = smask + b * N;
    float4 run = make_float4(-INFINITY, -INFINITY, -INFINITY, -INFINITY);
    int k = 0;
#pragma unroll
    for (int t = 0; t < 4; ++t) {
        int off = w + 4 * t;
        int e_t = s + off;
        for (; k <= off; ++k) {
            int e = s + k;
            if (e >= N) break;
            run = max4(run, prow[(size_t)e * D4]);
        }
        if (e_t < N) {
            float m = sm[e_t];
            orow[(size_t)e_t * D4] = make_float4(run.x * m, run.y * m, run.z * m, run.w * m);
        }
    }
}

// Kernel C: bounds ([B,N,N,2], stored as float) and mask2d ([B,N,N], float).
__global__ void fill_meta_kernel(const float* __restrict__ smask,
                                 const int* __restrict__ lengths,
                                 float2* __restrict__ bounds,
                                 float* __restrict__ m2d) {
    int blk = blockIdx.x;      // b*N + s
    int b = blk >> 7;
    int s = blk & (N - 1);
    int e = threadIdx.x;       // 128 threads
    float m = 0.0f;
    if (e >= s && e <= s + 15) m = smask[b * N + e];
    m2d[(size_t)blk * N + e] = m;
    int im = (int)m;
    int len1 = lengths[b] - 1;
    int b0 = min(s * 8, len1) * im;
    int b1 = min(e * 8 + 7, len1) * im;
    bounds[(size_t)blk * N + e] = make_float2((float)b0, (float)b1);
}

extern "C" void kernel_launch(void* const* d_in, const int* in_sizes, int n_in,
                              void* d_out, int out_size, void* d_ws, size_t ws_size,
                              hipStream_t stream) {
    const float* feats = (const float*)d_in[0];   // [B,T,D]
    const float* mask  = (const float*)d_in[1];   // [B,T]
    float* out = (float*)d_out;

    // workspace layout: pooled (B*N*D floats = 2MB), smask (B*N), lengths (B ints)
    float* pooled = (float*)d_ws;
    float* smask  = pooled + (size_t)B * N * D;
    int*   lengths = (int*)(smask + (size_t)B * N);

    hipLaunchKernelGGL(mask_stats_kernel, dim3(B), dim3(128), 0, stream,
                       mask, smask, lengths);
    hipLaunchKernelGGL(pool_feats_kernel, dim3(B * N / 4), dim3(256), 0, stream,
                       (const float4*)feats, mask, (float4*)pooled);
    hipLaunchKernelGGL(fill_feat2d_kernel, dim3(B * N), dim3(256), 0, stream,
                       (const float4*)pooled, smask, (float4*)out);

    float* bounds = out + (size_t)B * N * N * D;
    float* m2d    = bounds + (size_t)B * N * N * 2;
    hipLaunchKernelGGL(fill_meta_kernel, dim3(B * N), dim3(128), 0, stream,
                       smask, lengths, (float2*)bounds, m2d);
}

// Round 2
// 53.213 us; speedup vs baseline: 1.1092x; 1.1092x over previous
//
#include <hip/hip_runtime.h>

// Problem constants (fixed by setup_inputs): B=16, T=1024, D=256, SCALE=8 -> N=128
constexpr int B = 16;
constexpr int T = 1024;
constexpr int D = 256;
constexpr int N = 128;      // T / SCALE
constexpr int D4 = D / 4;   // 64 float4 per row
constexpr float NEG_INF_V = -1e30f;

__device__ __forceinline__ float4 max4(float4 a, float4 b) {
    return make_float4(fmaxf(a.x, b.x), fmaxf(a.y, b.y), fmaxf(a.z, b.z), fmaxf(a.w, b.w));
}

// Kernel P: pooled[b][n][:] = max over 8 frames of (feats + (1-mask)*NEG_INF),
//           smask[b*N+n]   = max over 8 frames of mask  (lane 0 only, free).
// grid: B*N/4 = 512 blocks x 256 threads; one 64-lane wave per pooled row n.
__global__ __launch_bounds__(256) void pool_feats_kernel(const float4* __restrict__ feats,
                                                         const float* __restrict__ mask,
                                                         float4* __restrict__ pooled,
                                                         float* __restrict__ smask) {
    int tid = threadIdx.x;
    int nloc = tid >> 6;                // 0..3
    int lane = tid & 63;                // float4 index over D
    int gidx = blockIdx.x * 4 + nloc;   // b*N + n
    int b = gidx >> 7;
    int n = gidx & (N - 1);
    const float* mrow = mask + (size_t)b * T + (size_t)n * 8;
    const float4* frow = feats + ((size_t)b * T + (size_t)n * 8) * D4 + lane;
    float4 acc = make_float4(-INFINITY, -INFINITY, -INFINITY, -INFINITY);
    float mmax = -INFINITY;
#pragma unroll
    for (int t = 0; t < 8; ++t) {
        float m = mrow[t];              // wave-uniform address -> broadcast
        mmax = fmaxf(mmax, m);
        float add = (1.0f - m) * NEG_INF_V;
        float4 v = frow[(size_t)t * D4];
        acc = max4(acc, make_float4(v.x + add, v.y + add, v.z + add, v.w + add));
    }
    pooled[(size_t)gidx * D4 + lane] = acc;
    if (lane == 0) smask[gidx] = mmax;
}

// Kernel F: everything else. One block per (b,s), 4 waves x 64 lanes.
//  - zero region: wave w writes contiguous rows [w*32, w*32+32) minus band rows
//  - band rows (s <= e <= s+15, e < N): prefix running max of pooled x smask[e]
//  - meta (threads 0..127): mask2d row + bounds row (length via wave shfl-reduce)
__global__ __launch_bounds__(256) void fill_all_kernel(const float4* __restrict__ pooled,
                                                       const float* __restrict__ smask,
                                                       const float4* __restrict__ mask4,
                                                       float4* __restrict__ out,
                                                       float2* __restrict__ bounds,
                                                       float* __restrict__ m2d) {
    int blk = blockIdx.x;              // b*N + s
    int b = blk >> 7;
    int s = blk & (N - 1);
    int w = threadIdx.x >> 6;          // wave id 0..3
    int lane = threadIdx.x & 63;       // float4 index over D

    float4 zero = make_float4(0.f, 0.f, 0.f, 0.f);
    float4* orow = out + ((size_t)blk * N) * D4 + lane;  // + e*D4

    // Zero region: contiguous 32-row chunk per wave (32 KB sequential stream).
    int band_hi = s + 15;
    int e0 = w * 32;
#pragma unroll 4
    for (int e = e0; e < e0 + 32; ++e) {
        if (e >= s && e <= band_hi) continue;            // band written below
        orow[(size_t)e * D4] = zero;
    }

    // Band: wave w writes offsets w, w+4, w+8, w+12 with prefix running max.
    const float4* prow = pooled + ((size_t)b * N) * D4 + lane;
    const float* sm = smask + b * N;
    float4 run = make_float4(-INFINITY, -INFINITY, -INFINITY, -INFINITY);
    int k = 0;
#pragma unroll
    for (int t = 0; t < 4; ++t) {
        int off = w + 4 * t;
        int e_t = s + off;
        for (; k <= off; ++k) {
            int e = s + k;
            if (e >= N) break;
            run = max4(run, prow[(size_t)e * D4]);
        }
        if (e_t < N) {
            float m = sm[e_t];
            orow[(size_t)e_t * D4] = make_float4(run.x * m, run.y * m, run.z * m, run.w * m);
        }
    }

    // Meta: threads 0..127 (waves 0 and 1). Each wave reduces the mask row for length.
    if (threadIdx.x < 128) {
        int e = threadIdx.x;
        const float4* mr = mask4 + (size_t)b * (T / 4);  // 256 float4 per batch
        float sum = 0.0f;
        for (int i = lane; i < T / 4; i += 64) {
            float4 v = mr[i];
            sum += v.x + v.y + v.z + v.w;
        }
#pragma unroll
        for (int d = 32; d > 0; d >>= 1) sum += __shfl_xor(sum, d, 64);
        int len1 = (int)sum - 1;

        float m = (e >= s && e <= band_hi) ? sm[e] : 0.0f;
        m2d[(size_t)blk * N + e] = m;
        int im = (int)m;
        int b0 = min(s * 8, len1) * im;
        int b1 = min(e * 8 + 7, len1) * im;
        bounds[(size_t)blk * N + e] = make_float2((float)b0, (float)b1);
    }
}

extern "C" void kernel_launch(void* const* d_in, const int* in_sizes, int n_in,
                              void* d_out, int out_size, void* d_ws, size_t ws_size,
                              hipStream_t stream) {
    const float* feats = (const float*)d_in[0];   // [B,T,D]
    const float* mask  = (const float*)d_in[1];   // [B,T]
    float* out = (float*)d_out;

    // workspace: pooled (B*N*D floats = 2 MB), smask (B*N floats)
    float* pooled = (float*)d_ws;
    float* smask  = pooled + (size_t)B * N * D;

    hipLaunchKernelGGL(pool_feats_kernel, dim3(B * N / 4), dim3(256), 0, stream,
                       (const float4*)feats, mask, (float4*)pooled, smask);

    float* bounds = out + (size_t)B * N * N * D;
    float* m2d    = bounds + (size_t)B * N * N * 2;
    hipLaunchKernelGGL(fill_all_kernel, dim3(B * N), dim3(256), 0, stream,
                       (const float4*)pooled, smask, (const float4*)mask,
                       (float4*)out, (float2*)bounds, m2d);
}